// Round 12
// baseline (117.119 us; speedup 1.0000x reference)
//
#include <hip/hip_runtime.h>
#include <math.h>

#define BATCH 2
#define SEQ   2048
#define DIM   1024
#define NH    16
#define HD    64
#define MTOT  4096

typedef __attribute__((ext_vector_type(8)))  short bf16x8;
typedef __attribute__((ext_vector_type(4)))  float f32x4;
typedef __attribute__((ext_vector_type(16))) float f32x16;
typedef __attribute__((ext_vector_type(2)))  float f32x2;
typedef __attribute__((ext_vector_type(2)))  unsigned u32x2;

__device__ __forceinline__ ushort f2bf(float f) {
    union { float f; unsigned u; } v; v.f = f;
    unsigned r = v.u + 0x7fffu + ((v.u >> 16) & 1u);
    return (ushort)(r >> 16);
}

__device__ __forceinline__ unsigned cvtpk_bf16(float lo, float hi) {
    unsigned r;
    asm("v_cvt_pk_bf16_f32 %0, %1, %2" : "=v"(r) : "v"(lo), "v"(hi));
    return r;
}

__device__ __forceinline__ f32x2 pk_add(f32x2 a, f32x2 b) {
    f32x2 d;
    asm("v_pk_add_f32 %0, %1, %2" : "=v"(d) : "v"(a), "v"(b));
    return d;
}

__device__ __forceinline__ f32x2 pk_mul(f32x2 a, f32x2 b) {
    f32x2 d;
    asm("v_pk_mul_f32 %0, %1, %2" : "=v"(d) : "v"(a), "v"(b));
    return d;
}

__device__ __forceinline__ float fmax3(float a, float b, float c) {
    return fmaxf(fmaxf(a, b), c);   // clang fuses to v_max3_f32
}

// ---------------------------------------------------------------------------
// fused cast: z=0 x (4M f4), z=1..4 Wq/Wk/Wv/Wo (1M f4 each)
// ---------------------------------------------------------------------------
__global__ __launch_bounds__(256)
void cast_all(const float* __restrict__ x,
              const float* __restrict__ Wq, const float* __restrict__ Wk,
              const float* __restrict__ Wv, const float* __restrict__ Wo,
              ushort* __restrict__ xb,
              ushort* __restrict__ wqb, ushort* __restrict__ wkb,
              ushort* __restrict__ wvb, ushort* __restrict__ wob)
{
    const int z = blockIdx.y;
    const float* s; ushort* d; int n4;
    if (z == 0)      { s = x;  d = xb;  n4 = MTOT * DIM / 4; }
    else if (z == 1) { s = Wq; d = wqb; n4 = DIM * DIM / 4; }
    else if (z == 2) { s = Wk; d = wkb; n4 = DIM * DIM / 4; }
    else if (z == 3) { s = Wv; d = wvb; n4 = DIM * DIM / 4; }
    else             { s = Wo; d = wob; n4 = DIM * DIM / 4; }
    for (int i = blockIdx.x * blockDim.x + threadIdx.x; i < n4;
         i += gridDim.x * blockDim.x) {
        float4 v = ((const float4*)s)[i];
        ushort4 o;
        o.x = f2bf(v.x); o.y = f2bf(v.y); o.z = f2bf(v.z); o.w = f2bf(v.w);
        ((ushort4*)d)[i] = o;
    }
}

// ---------------------------------------------------------------------------
// bf16 NT GEMM (R3 pipeline). MODE 0 writes FRAGMENT-MAJOR layouts via a
// 32KB LDS bounce -> coalesced dwordx4 stores.
//   z=0 Q*(0.125*log2e)  (exp2-domain scores), z=1 K, z=2 V^T
// MODE 1: fp32 [M,N] + bias.
// ---------------------------------------------------------------------------
template<int MODE>
__global__ __launch_bounds__(256)
void gemm_bf16(const ushort* __restrict__ A,
               const ushort* __restrict__ W0, const ushort* __restrict__ W1,
               const ushort* __restrict__ W2,
               ushort* __restrict__ D0, ushort* __restrict__ D1,
               ushort* __restrict__ D2,
               const float* __restrict__ bias, float* __restrict__ Fout)
{
    __shared__ __align__(16) ushort As[2][128 * 64];
    __shared__ __align__(16) ushort Bs[2][128 * 64];

    const int tid = threadIdx.x;
    const int w = tid >> 6, l = tid & 63;
    const int g = l >> 4, l15 = l & 15;
    const int wr = w >> 1, wc = w & 1;
    const int brow = blockIdx.x * 128, bcol = blockIdx.y * 128;

    const ushort* W = (MODE == 1) ? W0
                    : (blockIdx.z == 0 ? W0 : (blockIdx.z == 1 ? W1 : W2));
    ushort* Dst = (MODE == 1) ? (ushort*)0
                : (blockIdx.z == 0 ? D0 : (blockIdx.z == 1 ? D1 : D2));

    const int rsub = l >> 3;
    const int gc   = ((l & 7) ^ rsub) * 8;
    const size_t arow0 = (size_t)(brow + 32 * w + rsub) * DIM;
    const size_t brow0 = (size_t)(bcol + 32 * w + rsub) * DIM;

    auto STAGE = [&](int buf, int ktel) {
        #pragma unroll
        for (int i = 0; i < 4; ++i) {
            __builtin_amdgcn_global_load_lds(
                (const __attribute__((address_space(1))) void*)
                    &A[arow0 + (size_t)(8 * i) * DIM + ktel + gc],
                (__attribute__((address_space(3))) void*)
                    &As[buf][(32 * w + 8 * i) * 64], 16, 0, 0);
            __builtin_amdgcn_global_load_lds(
                (const __attribute__((address_space(1))) void*)
                    &W[brow0 + (size_t)(8 * i) * DIM + ktel + gc],
                (__attribute__((address_space(3))) void*)
                    &Bs[buf][(32 * w + 8 * i) * 64], 16, 0, 0);
        }
    };

    STAGE(0, 0);
    STAGE(1, 64);

    f32x4 acc[4][4] = {};

    for (int t = 0; t < 16; ++t) {
        const int cur = t & 1;
        if (t < 15) asm volatile("s_waitcnt vmcnt(8)" ::: "memory");
        else        asm volatile("s_waitcnt vmcnt(0)" ::: "memory");
        __builtin_amdgcn_s_barrier();
        __builtin_amdgcn_sched_barrier(0);

        #pragma unroll
        for (int kh = 0; kh < 2; ++kh) {
            bf16x8 af[4], bfr[4];
            #pragma unroll
            for (int mi = 0; mi < 4; ++mi) {
                int row = 64 * wr + 16 * mi + l15;
                af[mi] = *(const bf16x8*)&As[cur][row * 64 + (((4 * kh + g) ^ (row & 7)) * 8)];
            }
            #pragma unroll
            for (int nj = 0; nj < 4; ++nj) {
                int row = 64 * wc + 16 * nj + l15;
                bfr[nj] = *(const bf16x8*)&Bs[cur][row * 64 + (((4 * kh + g) ^ (row & 7)) * 8)];
            }
            __builtin_amdgcn_s_setprio(1);
            #pragma unroll
            for (int mi = 0; mi < 4; ++mi)
                #pragma unroll
                for (int nj = 0; nj < 4; ++nj)
                    acc[mi][nj] = __builtin_amdgcn_mfma_f32_16x16x32_bf16(
                        af[mi], bfr[nj], acc[mi][nj], 0, 0, 0);
            __builtin_amdgcn_s_setprio(0);
        }

        __builtin_amdgcn_sched_barrier(0);
        __builtin_amdgcn_s_barrier();
        if (t + 2 < 16) STAGE(cur, (t + 2) * 64);
    }

    if (MODE == 0) {
        ushort* LB = (ushort*)As;                    // 32 KB bounce
        const int bB = brow >> 11, t0 = brow & (SEQ - 1);
        if (blockIdx.z == 2) {
            #pragma unroll
            for (int mi = 0; mi < 4; ++mi)
                #pragma unroll
                for (int nj = 0; nj < 4; ++nj) {
                    int tlb = 64 * wr + 16 * mi + 4 * g;
                    int hd = 16 * nj + l15;
                    int sI = (tlb >> 3) * 2 + wc;
                    uint2 pk;
                    pk.x = cvtpk_bf16(acc[mi][nj][0], acc[mi][nj][1]);
                    pk.y = cvtpk_bf16(acc[mi][nj][2], acc[mi][nj][3]);
                    *(uint2*)&LB[sI * 512 + hd * 8 + (tlb & 7)] = pk;
                }
            __syncthreads();
            #pragma unroll
            for (int j = 0; j < 8; ++j) {
                int4 v = *(const int4*)&LB[(j * 256 + tid) * 8];
                int sI = j * 4 + (tid >> 6);
                size_t base = (size_t)(bB * NH + 2 * blockIdx.y + (sI & 1)) * (SEQ * HD)
                            + (size_t)((t0 >> 3) + (sI >> 1)) * 512 + (tid & 63) * 8;
                *(int4*)&Dst[base] = v;
            }
        } else {
            const float osc = (blockIdx.z == 0) ? 0.125f * 1.44269504f : 1.0f;
            #pragma unroll
            for (int mi = 0; mi < 4; ++mi)
                #pragma unroll
                for (int nj = 0; nj < 4; ++nj)
                    #pragma unroll
                    for (int reg = 0; reg < 4; ++reg) {
                        int tl = 64 * wr + 16 * mi + 4 * g + reg;
                        int hd = 16 * nj + l15;
                        int sI = (tl >> 5) * 2 + wc;
                        LB[sI * 2048 + (hd >> 3) * 256 + (tl & 31) * 8 + (hd & 7)] =
                            f2bf(acc[mi][nj][reg] * osc);
                    }
            __syncthreads();
            #pragma unroll
            for (int j = 0; j < 8; ++j) {
                int4 v = *(const int4*)&LB[(j * 256 + tid) * 8];
                size_t base = (size_t)(bB * NH + 2 * blockIdx.y + (j & 1)) * (SEQ * HD)
                            + (size_t)((t0 >> 5) + (j >> 1)) * 2048 + tid * 8;
                *(int4*)&Dst[base] = v;
            }
        }
    } else {
        #pragma unroll
        for (int nj = 0; nj < 4; ++nj) {
            int col = bcol + 64 * wc + 16 * nj + l15;
            float bv = bias[col];
            #pragma unroll
            for (int mi = 0; mi < 4; ++mi)
                #pragma unroll
                for (int reg = 0; reg < 4; ++reg) {
                    int row = brow + 64 * wr + 16 * mi + 4 * g + reg;
                    Fout[(size_t)row * DIM + col] = acc[mi][nj][reg] + bv;
                }
        }
    }
}

// ---------------------------------------------------------------------------
// Flash attention v10: paired-qt balanced persistent blocks. Block (bh,pair)
// processes qt=pair then qt=63-pair -> every block does 33-34 kv tiles.
// Grid 32x32 = 1024 blocks = exactly 4 blocks/CU, ALL resident, no tail.
// Per-half: split-KV across 4 waves (v9 body: reg-dbuf K/V, exp2-domain,
// max3 tree, pk-f32, cvt_pk+permlane P, setprio), LSE merge in LDS.
// ---------------------------------------------------------------------------
__global__ __launch_bounds__(256, 2)
void attn_mfma10(const ushort* __restrict__ q, const ushort* __restrict__ k,
                 const ushort* __restrict__ vt, ushort* __restrict__ ctx)
{
    __shared__ float Olds[4 * 2048];     // [w][d][q^(d&31)]  32 KB
    __shared__ float Mlds[4][32];
    __shared__ float Llds[4][32];

    const int tid = threadIdx.x;
    const int wq = tid >> 6, l = tid & 63;
    const int l31 = l & 31, h = l >> 5;
    const int bh = blockIdx.x;                // 0..31: XCD affinity = bh%8
    const int pair = blockIdx.y;              // 0..31

    const ushort* Qg = q  + (size_t)bh * SEQ * HD;
    const ushort* Kg = k  + (size_t)bh * SEQ * HD;
    const ushort* Vg = vt + (size_t)bh * SEQ * HD;

    #pragma unroll 1
    for (int half = 0; half < 2; ++half) {
        const int qt  = half ? (63 - pair) : pair;
        const int qlo = qt * 32;
        const int nt  = (qt >> 1) + 1;
        const int cnt = (nt + 3) >> 2;
        const int kt0 = wq * cnt;
        const int kt1 = min(nt, kt0 + cnt);

        bf16x8 qf[4];
        #pragma unroll
        for (int s = 0; s < 4; ++s)
            qf[s] = *(const bf16x8*)&Qg[(((size_t)qt * 8 + 2 * s + h) * 32 + l31) * 8];

        f32x16 o[2] = {};
        float m = -3.0e38f, lsum = 0.f;

        if (kt0 < kt1) {
            bf16x8 kfA[8], kfB[8], vfA[8], vfB[8];
            #pragma unroll
            for (int s = 0; s < 4; ++s)
                #pragma unroll
                for (int f = 0; f < 2; ++f)
                    kfA[2 * s + f] = *(const bf16x8*)
                        &Kg[(((size_t)(2 * kt0 + f) * 8 + 2 * s + h) * 32 + l31) * 8];
            #pragma unroll
            for (int s4 = 0; s4 < 4; ++s4)
                #pragma unroll
                for (int dt = 0; dt < 2; ++dt)
                    vfA[2 * s4 + dt] = *(const bf16x8*)
                        &Vg[(((size_t)(8 * kt0 + 2 * s4 + h)) * 64 + 32 * dt + l31) * 8];

            auto body = [&](bf16x8 (&kc)[8], bf16x8 (&kn)[8],
                            bf16x8 (&vc)[8], bf16x8 (&vn)[8], int kt) {
                const int kvb = 64 * kt;

                // S^T = K · Q^T  (already exp2-domain)
                f32x16 st[2] = {};
                __builtin_amdgcn_s_setprio(1);
                #pragma unroll
                for (int s = 0; s < 4; ++s)
                    #pragma unroll
                    for (int f = 0; f < 2; ++f)
                        st[f] = __builtin_amdgcn_mfma_f32_32x32x16_bf16(
                            kc[2 * s + f], qf[s], st[f], 0, 0, 0);
                __builtin_amdgcn_s_setprio(0);

                // prefetch next K and V tiles
                if (kt + 1 < kt1) {
                    #pragma unroll
                    for (int s = 0; s < 4; ++s)
                        #pragma unroll
                        for (int f = 0; f < 2; ++f)
                            kn[2 * s + f] = *(const bf16x8*)
                                &Kg[(((size_t)(2 * kt + 2 + f) * 8 + 2 * s + h) * 32 + l31) * 8];
                    #pragma unroll
                    for (int s4 = 0; s4 < 4; ++s4)
                        #pragma unroll
                        for (int dt = 0; dt < 2; ++dt)
                            vn[2 * s4 + dt] = *(const bf16x8*)
                                &Vg[(((size_t)(8 * kt + 8 + 2 * s4 + h)) * 64 + 32 * dt + l31) * 8];
                }

                // causal mask (only straddling tile)
                const int qg = qlo + l31;
                if (kvb + 63 > qlo) {
                    #pragma unroll
                    for (int f = 0; f < 2; ++f)
                        #pragma unroll
                        for (int r = 0; r < 16; ++r) {
                            int kvg = kvb + 32 * f + (r & 3) + 8 * (r >> 2) + 4 * h;
                            if (kvg > qg) st[f][r] = -INFINITY;
                        }
                }

                // row max via max3 chains
                float ca, cb;
                ca = fmax3(st[0][0], st[0][1], st[0][2]);
                cb = fmax3(st[0][3], st[0][4], st[0][5]);
                ca = fmax3(ca, st[0][6], st[0][7]);
                cb = fmax3(cb, st[0][8], st[0][9]);
                ca = fmax3(ca, st[0][10], st[0][11]);
                cb = fmax3(cb, st[0][12], st[0][13]);
                ca = fmax3(ca, st[0][14], st[0][15]);
                float t0 = fmaxf(ca, cb);
                ca = fmax3(st[1][0], st[1][1], st[1][2]);
                cb = fmax3(st[1][3], st[1][4], st[1][5]);
                ca = fmax3(ca, st[1][6], st[1][7]);
                cb = fmax3(cb, st[1][8], st[1][9]);
                ca = fmax3(ca, st[1][10], st[1][11]);
                cb = fmax3(cb, st[1][12], st[1][13]);
                ca = fmax3(ca, st[1][14], st[1][15]);
                float tmax = fmax3(t0, ca, cb);
                {
                    union { float f; unsigned u; } tm; tm.f = tmax;
                    u32x2 ts = __builtin_amdgcn_permlane32_swap(tm.u, tm.u, false, false);
                    union { unsigned u; float f; } to; to.u = h ? ts.x : ts.y;
                    tmax = fmaxf(tmax, to.f);
                }

                if (!__all(tmax - m <= 8.0f)) {          // T13 defer-max
                    float mn = fmaxf(m, tmax);
                    float sc = exp2f(m - mn);
                    lsum *= sc;
                    f32x2 sc2 = {sc, sc};
                    #pragma unroll
                    for (int dt = 0; dt < 2; ++dt) {
                        f32x2* po = (f32x2*)&o[dt];
                        #pragma unroll
                        for (int i = 0; i < 8; ++i) po[i] = pk_mul(po[i], sc2);
                    }
                    m = mn;
                }

                // exp + packed sums
                f32x2 mneg = {-m, -m};
                f32x2 a0 = {0.f, 0.f}, a1 = {0.f, 0.f}, a2 = {0.f, 0.f}, a3 = {0.f, 0.f};
                #pragma unroll
                for (int f = 0; f < 2; ++f) {
                    f32x2* pp = (f32x2*)&st[f];
                    #pragma unroll
                    for (int i = 0; i < 8; ++i) {
                        f32x2 t = pk_add(pp[i], mneg);
                        t.x = exp2f(t.x); t.y = exp2f(t.y);
                        pp[i] = t;
                        if ((i & 3) == 0)      a0 = pk_add(a0, t);
                        else if ((i & 3) == 1) a1 = pk_add(a1, t);
                        else if ((i & 3) == 2) a2 = pk_add(a2, t);
                        else                   a3 = pk_add(a3, t);
                    }
                }
                a0 = pk_add(a0, a1);
                a2 = pk_add(a2, a3);
                a0 = pk_add(a0, a2);
                lsum += a0.x + a0.y;

                // P -> PA frags: cvt_pk + permlane32_swap (T12), PV MFMAs
                #pragma unroll
                for (int s4 = 0; s4 < 4; ++s4) {
                    const int f = s4 >> 1, rb2 = 8 * (s4 & 1);
                    unsigned Aa = cvtpk_bf16(st[f][rb2 + 0], st[f][rb2 + 1]);
                    unsigned Bb = cvtpk_bf16(st[f][rb2 + 2], st[f][rb2 + 3]);
                    unsigned Cc = cvtpk_bf16(st[f][rb2 + 4], st[f][rb2 + 5]);
                    unsigned Dd = cvtpk_bf16(st[f][rb2 + 6], st[f][rb2 + 7]);
                    u32x2 r02 = __builtin_amdgcn_permlane32_swap(Aa, Cc, false, false);
                    u32x2 r13 = __builtin_amdgcn_permlane32_swap(Bb, Dd, false, false);
                    union { unsigned wv[4]; bf16x8 v; } pu;
                    pu.wv[0] = r02.x;
                    pu.wv[1] = r13.x;
                    pu.wv[2] = r02.y;
                    pu.wv[3] = r13.y;
                    __builtin_amdgcn_s_setprio(1);
                    #pragma unroll
                    for (int dt = 0; dt < 2; ++dt)
                        o[dt] = __builtin_amdgcn_mfma_f32_32x32x16_bf16(
                            vc[2 * s4 + dt], pu.v, o[dt], 0, 0, 0);
                    __builtin_amdgcn_s_setprio(0);
                }
            };

            int kt = kt0;
            while (true) {
                body(kfA, kfB, vfA, vfB, kt);
                if (++kt >= kt1) break;
                body(kfB, kfA, vfB, vfA, kt);
                if (++kt >= kt1) break;
            }
        }

        // ---- LSE merge across the block's 4 waves ----
        float lt = lsum + __shfl_xor(lsum, 32);
        if (h == 0) Mlds[wq][l31] = m;
        __syncthreads();
        float ms = fmaxf(fmaxf(Mlds[0][l31], Mlds[1][l31]),
                         fmaxf(Mlds[2][l31], Mlds[3][l31]));
        float fw = exp2f(m - ms);
        if (h == 0) Llds[wq][l31] = lt * fw;
        #pragma unroll
        for (int dt = 0; dt < 2; ++dt)
            #pragma unroll
            for (int r = 0; r < 16; ++r) {
                int d = 32 * dt + (r & 3) + 8 * (r >> 2) + 4 * h;
                Olds[wq * 2048 + d * 32 + (l31 ^ (d & 31))] = o[dt][r] * fw;
            }
        __syncthreads();

        // combine + coalesced write: thread -> (q = tid>>3, d-chunk = tid&7)
        const int tq = tid >> 3, tc = tid & 7;
        float inv = 1.0f / (Llds[0][tq] + Llds[1][tq] + Llds[2][tq] + Llds[3][tq]);
        union { ushort u[8]; int4 v4; } ov;
        #pragma unroll
        for (int i = 0; i < 8; i += 2) {
            int d0 = 8 * tc + i, d1 = d0 + 1;
            float s0 = 0.f, s1 = 0.f;
            #pragma unroll
            for (int ww = 0; ww < 4; ++ww) {
                s0 += Olds[ww * 2048 + d0 * 32 + (tq ^ (d0 & 31))];
                s1 += Olds[ww * 2048 + d1 * 32 + (tq ^ (d1 & 31))];
            }
            *(unsigned*)&ov.u[i] = cvtpk_bf16(s0 * inv, s1 * inv);
        }
        ushort* Cg = ctx + (size_t)bh * SEQ * HD + (size_t)qlo * HD;
        *(int4*)&Cg[tq * 64 + 8 * tc] = ov.v4;
    }
}

// ---------------------------------------------------------------------------
extern "C" void kernel_launch(void* const* d_in, const int* in_sizes, int n_in,
                              void* d_out, int out_size, void* d_ws, size_t ws_size,
                              hipStream_t stream)
{
    (void)in_sizes; (void)n_in; (void)out_size; (void)ws_size;
    const float* x  = (const float*)d_in[0];
    const float* Wq = (const float*)d_in[1];
    const float* Wk = (const float*)d_in[2];
    const float* Wv = (const float*)d_in[3];
    const float* Wo = (const float*)d_in[4];
    const float* bo = (const float*)d_in[5];
    float* out = (float*)d_out;

    ushort* wsu  = (ushort*)d_ws;
    ushort* xb   = wsu;                      // 4M
    ushort* wqb  = wsu + 4194304;            // 1M each
    ushort* wkb  = wsu + 5242880;
    ushort* wvb  = wsu + 6291456;
    ushort* wob  = wsu + 7340032;
    ushort* qbuf = wsu + 8388608;            // 4M, Q fragment-major, *0.125*log2e
    ushort* kbuf = wsu + 12582912;           // 4M, K fragment-major
    ushort* vtb  = wsu + 16777216;           // 4M, V^T fragment-major
    ushort* ctxb = wsu + 20971520;           // 4M, flat == [B*T, D]

    cast_all<<<dim3(512, 5), 256, 0, stream>>>(x, Wq, Wk, Wv, Wo,
                                               xb, wqb, wkb, wvb, wob);

    dim3 gqkv(MTOT / 128, DIM / 128, 3);
    gemm_bf16<0><<<gqkv, 256, 0, stream>>>(xb, wqb, wkb, wvb,
                                           qbuf, kbuf, vtb, nullptr, nullptr);

    dim3 ga(BATCH * NH, SEQ / 64);
    attn_mfma10<<<ga, 256, 0, stream>>>(qbuf, kbuf, vtb, ctxb);

    dim3 go(MTOT / 128, DIM / 128, 1);
    gemm_bf16<1><<<go, 256, 0, stream>>>(ctxb, wob, nullptr, nullptr,
                                         nullptr, nullptr, nullptr, bo, out);
}

// Round 13
// 106.420 us; speedup vs baseline: 1.1005x; 1.1005x over previous
//
#include <hip/hip_runtime.h>
#include <math.h>

#define BATCH 2
#define SEQ   2048
#define DIM   1024
#define NH    16
#define HD    64
#define MTOT  4096

typedef __attribute__((ext_vector_type(8)))  short bf16x8;
typedef __attribute__((ext_vector_type(4)))  float f32x4;
typedef __attribute__((ext_vector_type(16))) float f32x16;
typedef __attribute__((ext_vector_type(2)))  float f32x2;
typedef __attribute__((ext_vector_type(2)))  unsigned u32x2;

__device__ __forceinline__ ushort f2bf(float f) {
    union { float f; unsigned u; } v; v.f = f;
    unsigned r = v.u + 0x7fffu + ((v.u >> 16) & 1u);
    return (ushort)(r >> 16);
}

__device__ __forceinline__ unsigned cvtpk_bf16(float lo, float hi) {
    unsigned r;
    asm("v_cvt_pk_bf16_f32 %0, %1, %2" : "=v"(r) : "v"(lo), "v"(hi));
    return r;
}

__device__ __forceinline__ f32x2 pk_add(f32x2 a, f32x2 b) {
    f32x2 d;
    asm("v_pk_add_f32 %0, %1, %2" : "=v"(d) : "v"(a), "v"(b));
    return d;
}

__device__ __forceinline__ f32x2 pk_mul(f32x2 a, f32x2 b) {
    f32x2 d;
    asm("v_pk_mul_f32 %0, %1, %2" : "=v"(d) : "v"(a), "v"(b));
    return d;
}

__device__ __forceinline__ float fmax3(float a, float b, float c) {
    return fmaxf(fmaxf(a, b), c);   // clang fuses to v_max3_f32
}

// ---------------------------------------------------------------------------
// fused cast: z=0 x (4M f4), z=1..4 Wq/Wk/Wv/Wo (1M f4 each)
// ---------------------------------------------------------------------------
__global__ __launch_bounds__(256)
void cast_all(const float* __restrict__ x,
              const float* __restrict__ Wq, const float* __restrict__ Wk,
              const float* __restrict__ Wv, const float* __restrict__ Wo,
              ushort* __restrict__ xb,
              ushort* __restrict__ wqb, ushort* __restrict__ wkb,
              ushort* __restrict__ wvb, ushort* __restrict__ wob)
{
    const int z = blockIdx.y;
    const float* s; ushort* d; int n4;
    if (z == 0)      { s = x;  d = xb;  n4 = MTOT * DIM / 4; }
    else if (z == 1) { s = Wq; d = wqb; n4 = DIM * DIM / 4; }
    else if (z == 2) { s = Wk; d = wkb; n4 = DIM * DIM / 4; }
    else if (z == 3) { s = Wv; d = wvb; n4 = DIM * DIM / 4; }
    else             { s = Wo; d = wob; n4 = DIM * DIM / 4; }
    for (int i = blockIdx.x * blockDim.x + threadIdx.x; i < n4;
         i += gridDim.x * blockDim.x) {
        float4 v = ((const float4*)s)[i];
        ushort4 o;
        o.x = f2bf(v.x); o.y = f2bf(v.y); o.z = f2bf(v.z); o.w = f2bf(v.w);
        ((ushort4*)d)[i] = o;
    }
}

// ---------------------------------------------------------------------------
// bf16 NT GEMM (R3 pipeline). MODE 0 writes FRAGMENT-MAJOR layouts via a
// 32KB LDS bounce -> coalesced dwordx4 stores.
//   z=0 Q*(0.125*log2e)  (exp2-domain scores), z=1 K, z=2 V^T
// MODE 1: fp32 [M,N] + bias.
// ---------------------------------------------------------------------------
template<int MODE>
__global__ __launch_bounds__(256)
void gemm_bf16(const ushort* __restrict__ A,
               const ushort* __restrict__ W0, const ushort* __restrict__ W1,
               const ushort* __restrict__ W2,
               ushort* __restrict__ D0, ushort* __restrict__ D1,
               ushort* __restrict__ D2,
               const float* __restrict__ bias, float* __restrict__ Fout)
{
    __shared__ __align__(16) ushort As[2][128 * 64];
    __shared__ __align__(16) ushort Bs[2][128 * 64];

    const int tid = threadIdx.x;
    const int w = tid >> 6, l = tid & 63;
    const int g = l >> 4, l15 = l & 15;
    const int wr = w >> 1, wc = w & 1;
    const int brow = blockIdx.x * 128, bcol = blockIdx.y * 128;

    const ushort* W = (MODE == 1) ? W0
                    : (blockIdx.z == 0 ? W0 : (blockIdx.z == 1 ? W1 : W2));
    ushort* Dst = (MODE == 1) ? (ushort*)0
                : (blockIdx.z == 0 ? D0 : (blockIdx.z == 1 ? D1 : D2));

    const int rsub = l >> 3;
    const int gc   = ((l & 7) ^ rsub) * 8;
    const size_t arow0 = (size_t)(brow + 32 * w + rsub) * DIM;
    const size_t brow0 = (size_t)(bcol + 32 * w + rsub) * DIM;

    auto STAGE = [&](int buf, int ktel) {
        #pragma unroll
        for (int i = 0; i < 4; ++i) {
            __builtin_amdgcn_global_load_lds(
                (const __attribute__((address_space(1))) void*)
                    &A[arow0 + (size_t)(8 * i) * DIM + ktel + gc],
                (__attribute__((address_space(3))) void*)
                    &As[buf][(32 * w + 8 * i) * 64], 16, 0, 0);
            __builtin_amdgcn_global_load_lds(
                (const __attribute__((address_space(1))) void*)
                    &W[brow0 + (size_t)(8 * i) * DIM + ktel + gc],
                (__attribute__((address_space(3))) void*)
                    &Bs[buf][(32 * w + 8 * i) * 64], 16, 0, 0);
        }
    };

    STAGE(0, 0);
    STAGE(1, 64);

    f32x4 acc[4][4] = {};

    for (int t = 0; t < 16; ++t) {
        const int cur = t & 1;
        if (t < 15) asm volatile("s_waitcnt vmcnt(8)" ::: "memory");
        else        asm volatile("s_waitcnt vmcnt(0)" ::: "memory");
        __builtin_amdgcn_s_barrier();
        __builtin_amdgcn_sched_barrier(0);

        #pragma unroll
        for (int kh = 0; kh < 2; ++kh) {
            bf16x8 af[4], bfr[4];
            #pragma unroll
            for (int mi = 0; mi < 4; ++mi) {
                int row = 64 * wr + 16 * mi + l15;
                af[mi] = *(const bf16x8*)&As[cur][row * 64 + (((4 * kh + g) ^ (row & 7)) * 8)];
            }
            #pragma unroll
            for (int nj = 0; nj < 4; ++nj) {
                int row = 64 * wc + 16 * nj + l15;
                bfr[nj] = *(const bf16x8*)&Bs[cur][row * 64 + (((4 * kh + g) ^ (row & 7)) * 8)];
            }
            __builtin_amdgcn_s_setprio(1);
            #pragma unroll
            for (int mi = 0; mi < 4; ++mi)
                #pragma unroll
                for (int nj = 0; nj < 4; ++nj)
                    acc[mi][nj] = __builtin_amdgcn_mfma_f32_16x16x32_bf16(
                        af[mi], bfr[nj], acc[mi][nj], 0, 0, 0);
            __builtin_amdgcn_s_setprio(0);
        }

        __builtin_amdgcn_sched_barrier(0);
        __builtin_amdgcn_s_barrier();
        if (t + 2 < 16) STAGE(cur, (t + 2) * 64);
    }

    if (MODE == 0) {
        ushort* LB = (ushort*)As;                    // 32 KB bounce
        const int bB = brow >> 11, t0 = brow & (SEQ - 1);
        if (blockIdx.z == 2) {
            #pragma unroll
            for (int mi = 0; mi < 4; ++mi)
                #pragma unroll
                for (int nj = 0; nj < 4; ++nj) {
                    int tlb = 64 * wr + 16 * mi + 4 * g;
                    int hd = 16 * nj + l15;
                    int sI = (tlb >> 3) * 2 + wc;
                    uint2 pk;
                    pk.x = cvtpk_bf16(acc[mi][nj][0], acc[mi][nj][1]);
                    pk.y = cvtpk_bf16(acc[mi][nj][2], acc[mi][nj][3]);
                    *(uint2*)&LB[sI * 512 + hd * 8 + (tlb & 7)] = pk;
                }
            __syncthreads();
            #pragma unroll
            for (int j = 0; j < 8; ++j) {
                int4 v = *(const int4*)&LB[(j * 256 + tid) * 8];
                int sI = j * 4 + (tid >> 6);
                size_t base = (size_t)(bB * NH + 2 * blockIdx.y + (sI & 1)) * (SEQ * HD)
                            + (size_t)((t0 >> 3) + (sI >> 1)) * 512 + (tid & 63) * 8;
                *(int4*)&Dst[base] = v;
            }
        } else {
            const float osc = (blockIdx.z == 0) ? 0.125f * 1.44269504f : 1.0f;
            #pragma unroll
            for (int mi = 0; mi < 4; ++mi)
                #pragma unroll
                for (int nj = 0; nj < 4; ++nj)
                    #pragma unroll
                    for (int reg = 0; reg < 4; ++reg) {
                        int tl = 64 * wr + 16 * mi + 4 * g + reg;
                        int hd = 16 * nj + l15;
                        int sI = (tl >> 5) * 2 + wc;
                        LB[sI * 2048 + (hd >> 3) * 256 + (tl & 31) * 8 + (hd & 7)] =
                            f2bf(acc[mi][nj][reg] * osc);
                    }
            __syncthreads();
            #pragma unroll
            for (int j = 0; j < 8; ++j) {
                int4 v = *(const int4*)&LB[(j * 256 + tid) * 8];
                size_t base = (size_t)(bB * NH + 2 * blockIdx.y + (j & 1)) * (SEQ * HD)
                            + (size_t)((t0 >> 5) + (j >> 1)) * 2048 + tid * 8;
                *(int4*)&Dst[base] = v;
            }
        }
    } else {
        #pragma unroll
        for (int nj = 0; nj < 4; ++nj) {
            int col = bcol + 64 * wc + 16 * nj + l15;
            float bv = bias[col];
            #pragma unroll
            for (int mi = 0; mi < 4; ++mi)
                #pragma unroll
                for (int reg = 0; reg < 4; ++reg) {
                    int row = brow + 64 * wr + 16 * mi + 4 * g + reg;
                    Fout[(size_t)row * DIM + col] = acc[mi][nj][reg] + bv;
                }
        }
    }
}

// ---------------------------------------------------------------------------
// Flash attention v11 = v9 structure (grid 32x64 longest-first, 4-wave
// split-KV, LSE merge) + T15 QK-ahead pipeline: tile kt+1's QK^T MFMAs are
// issued BEFORE tile kt's softmax so the MFMA pipe drains under the VALU
// burst. K double-buffered (QK-ahead consumes K one body early); V single-
// buffered, loaded at body top (L2-resident, hides under QK-next+softmax).
// ---------------------------------------------------------------------------
__global__ __launch_bounds__(256, 2)
void attn_mfma11(const ushort* __restrict__ q, const ushort* __restrict__ k,
                 const ushort* __restrict__ vt, ushort* __restrict__ ctx)
{
    __shared__ float Olds[4 * 2048];     // [w][d][q^(d&31)]  32 KB
    __shared__ float Mlds[4][32];
    __shared__ float Llds[4][32];

    const int tid = threadIdx.x;
    const int wq = tid >> 6, l = tid & 63;
    const int l31 = l & 31, h = l >> 5;
    const int bh = blockIdx.x;                // 0..31: XCD affinity = bh%8
    const int qt = 63 - (int)blockIdx.y;      // longest-first
    const int qlo = qt * 32;
    const int nt  = (qt >> 1) + 1;
    const int cnt = (nt + 3) >> 2;
    const int kt0 = wq * cnt;
    const int kt1 = min(nt, kt0 + cnt);

    const ushort* Qg = q  + (size_t)bh * SEQ * HD;
    const ushort* Kg = k  + (size_t)bh * SEQ * HD;
    const ushort* Vg = vt + (size_t)bh * SEQ * HD;

    bf16x8 qf[4];
    #pragma unroll
    for (int s = 0; s < 4; ++s)
        qf[s] = *(const bf16x8*)&Qg[(((size_t)qt * 8 + 2 * s + h) * 32 + l31) * 8];

    f32x16 o[2] = {};
    float m = -3.0e38f, lsum = 0.f;

    if (kt0 < kt1) {
        bf16x8 kfA[8], kfB[8];
        f32x16 stA[2], stB[2];

        // prologue: K(kt0) -> kfA; QK(kt0) -> stA; K(kt0+1) -> kfB
        #pragma unroll
        for (int s = 0; s < 4; ++s)
            #pragma unroll
            for (int f = 0; f < 2; ++f)
                kfA[2 * s + f] = *(const bf16x8*)
                    &Kg[(((size_t)(2 * kt0 + f) * 8 + 2 * s + h) * 32 + l31) * 8];
        stA[0] = (f32x16){}; stA[1] = (f32x16){};
        #pragma unroll
        for (int s = 0; s < 4; ++s)
            #pragma unroll
            for (int f = 0; f < 2; ++f)
                stA[f] = __builtin_amdgcn_mfma_f32_32x32x16_bf16(
                    kfA[2 * s + f], qf[s], stA[f], 0, 0, 0);
        if (kt0 + 1 < kt1) {
            #pragma unroll
            for (int s = 0; s < 4; ++s)
                #pragma unroll
                for (int f = 0; f < 2; ++f)
                    kfB[2 * s + f] = *(const bf16x8*)
                        &Kg[(((size_t)(2 * kt0 + 2 + f) * 8 + 2 * s + h) * 32 + l31) * 8];
        }

        // body: consume stC (tile kt); build stN (tile kt+1) from kcN;
        //       load K(kt+2) into kcL; V loaded in-body.
        auto body = [&](f32x16 (&stC)[2], f32x16 (&stN)[2],
                        bf16x8 (&kcN)[8], bf16x8 (&kcL)[8], int kt) {
            const int kvb = 64 * kt;

            // V loads for current tile (used ~300cy later in PV)
            bf16x8 vf[8];
            #pragma unroll
            for (int s4 = 0; s4 < 4; ++s4)
                #pragma unroll
                for (int dt = 0; dt < 2; ++dt)
                    vf[2 * s4 + dt] = *(const bf16x8*)
                        &Vg[(((size_t)(8 * kt + 2 * s4 + h)) * 64 + 32 * dt + l31) * 8];

            // QK^T for NEXT tile (MFMA pipe drains under this body's softmax)
            if (kt + 1 < kt1) {
                stN[0] = (f32x16){}; stN[1] = (f32x16){};
                __builtin_amdgcn_s_setprio(1);
                #pragma unroll
                for (int s = 0; s < 4; ++s)
                    #pragma unroll
                    for (int f = 0; f < 2; ++f)
                        stN[f] = __builtin_amdgcn_mfma_f32_32x32x16_bf16(
                            kcN[2 * s + f], qf[s], stN[f], 0, 0, 0);
                __builtin_amdgcn_s_setprio(0);
            }

            // K load for kt+2 (double buffer)
            if (kt + 2 < kt1) {
                #pragma unroll
                for (int s = 0; s < 4; ++s)
                    #pragma unroll
                    for (int f = 0; f < 2; ++f)
                        kcL[2 * s + f] = *(const bf16x8*)
                            &Kg[(((size_t)(2 * kt + 4 + f) * 8 + 2 * s + h) * 32 + l31) * 8];
            }

            // causal mask (only straddling tile)
            const int qg = qlo + l31;
            if (kvb + 63 > qlo) {
                #pragma unroll
                for (int f = 0; f < 2; ++f)
                    #pragma unroll
                    for (int r = 0; r < 16; ++r) {
                        int kvg = kvb + 32 * f + (r & 3) + 8 * (r >> 2) + 4 * h;
                        if (kvg > qg) stC[f][r] = -INFINITY;
                    }
            }

            // row max via max3 chains
            float ca, cb;
            ca = fmax3(stC[0][0], stC[0][1], stC[0][2]);
            cb = fmax3(stC[0][3], stC[0][4], stC[0][5]);
            ca = fmax3(ca, stC[0][6], stC[0][7]);
            cb = fmax3(cb, stC[0][8], stC[0][9]);
            ca = fmax3(ca, stC[0][10], stC[0][11]);
            cb = fmax3(cb, stC[0][12], stC[0][13]);
            ca = fmax3(ca, stC[0][14], stC[0][15]);
            float t0 = fmaxf(ca, cb);
            ca = fmax3(stC[1][0], stC[1][1], stC[1][2]);
            cb = fmax3(stC[1][3], stC[1][4], stC[1][5]);
            ca = fmax3(ca, stC[1][6], stC[1][7]);
            cb = fmax3(cb, stC[1][8], stC[1][9]);
            ca = fmax3(ca, stC[1][10], stC[1][11]);
            cb = fmax3(cb, stC[1][12], stC[1][13]);
            ca = fmax3(ca, stC[1][14], stC[1][15]);
            float tmax = fmax3(t0, ca, cb);
            {
                union { float f; unsigned u; } tm; tm.f = tmax;
                u32x2 ts = __builtin_amdgcn_permlane32_swap(tm.u, tm.u, false, false);
                union { unsigned u; float f; } to; to.u = h ? ts.x : ts.y;
                tmax = fmaxf(tmax, to.f);
            }

            if (!__all(tmax - m <= 8.0f)) {          // T13 defer-max
                float mn = fmaxf(m, tmax);
                float sc = exp2f(m - mn);
                lsum *= sc;
                f32x2 sc2 = {sc, sc};
                #pragma unroll
                for (int dt = 0; dt < 2; ++dt) {
                    f32x2* po = (f32x2*)&o[dt];
                    #pragma unroll
                    for (int i = 0; i < 8; ++i) po[i] = pk_mul(po[i], sc2);
                }
                m = mn;
            }

            // exp + packed sums
            f32x2 mneg = {-m, -m};
            f32x2 a0 = {0.f, 0.f}, a1 = {0.f, 0.f}, a2 = {0.f, 0.f}, a3 = {0.f, 0.f};
            #pragma unroll
            for (int f = 0; f < 2; ++f) {
                f32x2* pp = (f32x2*)&stC[f];
                #pragma unroll
                for (int i = 0; i < 8; ++i) {
                    f32x2 t = pk_add(pp[i], mneg);
                    t.x = exp2f(t.x); t.y = exp2f(t.y);
                    pp[i] = t;
                    if ((i & 3) == 0)      a0 = pk_add(a0, t);
                    else if ((i & 3) == 1) a1 = pk_add(a1, t);
                    else if ((i & 3) == 2) a2 = pk_add(a2, t);
                    else                   a3 = pk_add(a3, t);
                }
            }
            a0 = pk_add(a0, a1);
            a2 = pk_add(a2, a3);
            a0 = pk_add(a0, a2);
            lsum += a0.x + a0.y;

            // P -> PA frags: cvt_pk + permlane32_swap (T12), PV MFMAs
            #pragma unroll
            for (int s4 = 0; s4 < 4; ++s4) {
                const int f = s4 >> 1, rb2 = 8 * (s4 & 1);
                unsigned Aa = cvtpk_bf16(stC[f][rb2 + 0], stC[f][rb2 + 1]);
                unsigned Bb = cvtpk_bf16(stC[f][rb2 + 2], stC[f][rb2 + 3]);
                unsigned Cc = cvtpk_bf16(stC[f][rb2 + 4], stC[f][rb2 + 5]);
                unsigned Dd = cvtpk_bf16(stC[f][rb2 + 6], stC[f][rb2 + 7]);
                u32x2 r02 = __builtin_amdgcn_permlane32_swap(Aa, Cc, false, false);
                u32x2 r13 = __builtin_amdgcn_permlane32_swap(Bb, Dd, false, false);
                union { unsigned wv[4]; bf16x8 v; } pu;
                pu.wv[0] = r02.x;
                pu.wv[1] = r13.x;
                pu.wv[2] = r02.y;
                pu.wv[3] = r13.y;
                __builtin_amdgcn_s_setprio(1);
                #pragma unroll
                for (int dt = 0; dt < 2; ++dt)
                    o[dt] = __builtin_amdgcn_mfma_f32_32x32x16_bf16(
                        vf[2 * s4 + dt], pu.v, o[dt], 0, 0, 0);
                __builtin_amdgcn_s_setprio(0);
            }
        };

        int kt = kt0;
        while (true) {
            body(stA, stB, kfB, kfA, kt);
            if (++kt >= kt1) break;
            body(stB, stA, kfA, kfB, kt);
            if (++kt >= kt1) break;
        }
    }

    // ---- LSE merge across the block's 4 waves ----
    float lt = lsum + __shfl_xor(lsum, 32);
    if (h == 0) Mlds[wq][l31] = m;
    __syncthreads();
    float ms = fmaxf(fmaxf(Mlds[0][l31], Mlds[1][l31]),
                     fmaxf(Mlds[2][l31], Mlds[3][l31]));
    float fw = exp2f(m - ms);
    if (h == 0) Llds[wq][l31] = lt * fw;
    #pragma unroll
    for (int dt = 0; dt < 2; ++dt)
        #pragma unroll
        for (int r = 0; r < 16; ++r) {
            int d = 32 * dt + (r & 3) + 8 * (r >> 2) + 4 * h;
            Olds[wq * 2048 + d * 32 + (l31 ^ (d & 31))] = o[dt][r] * fw;
        }
    __syncthreads();

    // combine + coalesced write: thread -> (q = tid>>3, d-chunk = tid&7)
    const int tq = tid >> 3, tc = tid & 7;
    float inv = 1.0f / (Llds[0][tq] + Llds[1][tq] + Llds[2][tq] + Llds[3][tq]);
    union { ushort u[8]; int4 v4; } ov;
    #pragma unroll
    for (int i = 0; i < 8; i += 2) {
        int d0 = 8 * tc + i, d1 = d0 + 1;
        float s0 = 0.f, s1 = 0.f;
        #pragma unroll
        for (int ww = 0; ww < 4; ++ww) {
            s0 += Olds[ww * 2048 + d0 * 32 + (tq ^ (d0 & 31))];
            s1 += Olds[ww * 2048 + d1 * 32 + (tq ^ (d1 & 31))];
        }
        *(unsigned*)&ov.u[i] = cvtpk_bf16(s0 * inv, s1 * inv);
    }
    ushort* Cg = ctx + (size_t)bh * SEQ * HD + (size_t)qlo * HD;
    *(int4*)&Cg[tq * 64 + 8 * tc] = ov.v4;
}

// ---------------------------------------------------------------------------
extern "C" void kernel_launch(void* const* d_in, const int* in_sizes, int n_in,
                              void* d_out, int out_size, void* d_ws, size_t ws_size,
                              hipStream_t stream)
{
    (void)in_sizes; (void)n_in; (void)out_size; (void)ws_size;
    const float* x  = (const float*)d_in[0];
    const float* Wq = (const float*)d_in[1];
    const float* Wk = (const float*)d_in[2];
    const float* Wv = (const float*)d_in[3];
    const float* Wo = (const float*)d_in[4];
    const float* bo = (const float*)d_in[5];
    float* out = (float*)d_out;

    ushort* wsu  = (ushort*)d_ws;
    ushort* xb   = wsu;                      // 4M
    ushort* wqb  = wsu + 4194304;            // 1M each
    ushort* wkb  = wsu + 5242880;
    ushort* wvb  = wsu + 6291456;
    ushort* wob  = wsu + 7340032;
    ushort* qbuf = wsu + 8388608;            // 4M, Q fragment-major, *0.125*log2e
    ushort* kbuf = wsu + 12582912;           // 4M, K fragment-major
    ushort* vtb  = wsu + 16777216;           // 4M, V^T fragment-major
    ushort* ctxb = wsu + 20971520;           // 4M, flat == [B*T, D]

    cast_all<<<dim3(512, 5), 256, 0, stream>>>(x, Wq, Wk, Wv, Wo,
                                               xb, wqb, wkb, wvb, wob);

    dim3 gqkv(MTOT / 128, DIM / 128, 3);
    gemm_bf16<0><<<gqkv, 256, 0, stream>>>(xb, wqb, wkb, wvb,
                                           qbuf, kbuf, vtb, nullptr, nullptr);

    dim3 ga(BATCH * NH, SEQ / 32);
    attn_mfma11<<<ga, 256, 0, stream>>>(qbuf, kbuf, vtb, ctxb);

    dim3 go(MTOT / 128, DIM / 128, 1);
    gemm_bf16<1><<<go, 256, 0, stream>>>(ctxb, wob, nullptr, nullptr,
                                         nullptr, nullptr, nullptr, bo, out);
}

// Round 14
// 102.050 us; speedup vs baseline: 1.1477x; 1.0428x over previous
//
#include <hip/hip_runtime.h>
#include <math.h>

#define BATCH 2
#define SEQ   2048
#define DIM   1024
#define NH    16
#define HD    64
#define MTOT  4096

typedef __attribute__((ext_vector_type(8)))  short bf16x8;
typedef __attribute__((ext_vector_type(4)))  float f32x4;
typedef __attribute__((ext_vector_type(16))) float f32x16;
typedef __attribute__((ext_vector_type(2)))  float f32x2;
typedef __attribute__((ext_vector_type(2)))  unsigned u32x2;

__device__ __forceinline__ ushort f2bf(float f) {
    union { float f; unsigned u; } v; v.f = f;
    unsigned r = v.u + 0x7fffu + ((v.u >> 16) & 1u);
    return (ushort)(r >> 16);
}

__device__ __forceinline__ unsigned cvtpk_bf16(float lo, float hi) {
    unsigned r;
    asm("v_cvt_pk_bf16_f32 %0, %1, %2" : "=v"(r) : "v"(lo), "v"(hi));
    return r;
}

__device__ __forceinline__ float exp2_asm(float x) {
    float r;
    asm("v_exp_f32 %0, %1" : "=v"(r) : "v"(x));
    return r;
}

__device__ __forceinline__ f32x2 pk_add(f32x2 a, f32x2 b) {
    f32x2 d;
    asm("v_pk_add_f32 %0, %1, %2" : "=v"(d) : "v"(a), "v"(b));
    return d;
}

__device__ __forceinline__ f32x2 pk_mul(f32x2 a, f32x2 b) {
    f32x2 d;
    asm("v_pk_mul_f32 %0, %1, %2" : "=v"(d) : "v"(a), "v"(b));
    return d;
}

__device__ __forceinline__ float fmax3(float a, float b, float c) {
    return fmaxf(fmaxf(a, b), c);   // clang fuses to v_max3_f32
}

// ---------------------------------------------------------------------------
// fused cast: z=0 x (4M f4), z=1..4 Wq/Wk/Wv/Wo (1M f4 each)
// ---------------------------------------------------------------------------
__global__ __launch_bounds__(256)
void cast_all(const float* __restrict__ x,
              const float* __restrict__ Wq, const float* __restrict__ Wk,
              const float* __restrict__ Wv, const float* __restrict__ Wo,
              ushort* __restrict__ xb,
              ushort* __restrict__ wqb, ushort* __restrict__ wkb,
              ushort* __restrict__ wvb, ushort* __restrict__ wob)
{
    const int z = blockIdx.y;
    const float* s; ushort* d; int n4;
    if (z == 0)      { s = x;  d = xb;  n4 = MTOT * DIM / 4; }
    else if (z == 1) { s = Wq; d = wqb; n4 = DIM * DIM / 4; }
    else if (z == 2) { s = Wk; d = wkb; n4 = DIM * DIM / 4; }
    else if (z == 3) { s = Wv; d = wvb; n4 = DIM * DIM / 4; }
    else             { s = Wo; d = wob; n4 = DIM * DIM / 4; }
    for (int i = blockIdx.x * blockDim.x + threadIdx.x; i < n4;
         i += gridDim.x * blockDim.x) {
        float4 v = ((const float4*)s)[i];
        ushort4 o;
        o.x = f2bf(v.x); o.y = f2bf(v.y); o.z = f2bf(v.z); o.w = f2bf(v.w);
        ((ushort4*)d)[i] = o;
    }
}

// ---------------------------------------------------------------------------
// bf16 NT GEMM (R3 pipeline). MODE 0 writes FRAGMENT-MAJOR layouts via a
// 32KB LDS bounce -> coalesced dwordx4 stores.
//   z=0 Q*(0.125*log2e)  (exp2-domain scores), z=1 K, z=2 V^T
// MODE 1: fp32 [M,N] + bias.
// ---------------------------------------------------------------------------
template<int MODE>
__global__ __launch_bounds__(256)
void gemm_bf16(const ushort* __restrict__ A,
               const ushort* __restrict__ W0, const ushort* __restrict__ W1,
               const ushort* __restrict__ W2,
               ushort* __restrict__ D0, ushort* __restrict__ D1,
               ushort* __restrict__ D2,
               const float* __restrict__ bias, float* __restrict__ Fout)
{
    __shared__ __align__(16) ushort As[2][128 * 64];
    __shared__ __align__(16) ushort Bs[2][128 * 64];

    const int tid = threadIdx.x;
    const int w = tid >> 6, l = tid & 63;
    const int g = l >> 4, l15 = l & 15;
    const int wr = w >> 1, wc = w & 1;
    const int brow = blockIdx.x * 128, bcol = blockIdx.y * 128;

    const ushort* W = (MODE == 1) ? W0
                    : (blockIdx.z == 0 ? W0 : (blockIdx.z == 1 ? W1 : W2));
    ushort* Dst = (MODE == 1) ? (ushort*)0
                : (blockIdx.z == 0 ? D0 : (blockIdx.z == 1 ? D1 : D2));

    const int rsub = l >> 3;
    const int gc   = ((l & 7) ^ rsub) * 8;
    const size_t arow0 = (size_t)(brow + 32 * w + rsub) * DIM;
    const size_t brow0 = (size_t)(bcol + 32 * w + rsub) * DIM;

    auto STAGE = [&](int buf, int ktel) {
        #pragma unroll
        for (int i = 0; i < 4; ++i) {
            __builtin_amdgcn_global_load_lds(
                (const __attribute__((address_space(1))) void*)
                    &A[arow0 + (size_t)(8 * i) * DIM + ktel + gc],
                (__attribute__((address_space(3))) void*)
                    &As[buf][(32 * w + 8 * i) * 64], 16, 0, 0);
            __builtin_amdgcn_global_load_lds(
                (const __attribute__((address_space(1))) void*)
                    &W[brow0 + (size_t)(8 * i) * DIM + ktel + gc],
                (__attribute__((address_space(3))) void*)
                    &Bs[buf][(32 * w + 8 * i) * 64], 16, 0, 0);
        }
    };

    STAGE(0, 0);
    STAGE(1, 64);

    f32x4 acc[4][4] = {};

    for (int t = 0; t < 16; ++t) {
        const int cur = t & 1;
        if (t < 15) asm volatile("s_waitcnt vmcnt(8)" ::: "memory");
        else        asm volatile("s_waitcnt vmcnt(0)" ::: "memory");
        __builtin_amdgcn_s_barrier();
        __builtin_amdgcn_sched_barrier(0);

        #pragma unroll
        for (int kh = 0; kh < 2; ++kh) {
            bf16x8 af[4], bfr[4];
            #pragma unroll
            for (int mi = 0; mi < 4; ++mi) {
                int row = 64 * wr + 16 * mi + l15;
                af[mi] = *(const bf16x8*)&As[cur][row * 64 + (((4 * kh + g) ^ (row & 7)) * 8)];
            }
            #pragma unroll
            for (int nj = 0; nj < 4; ++nj) {
                int row = 64 * wc + 16 * nj + l15;
                bfr[nj] = *(const bf16x8*)&Bs[cur][row * 64 + (((4 * kh + g) ^ (row & 7)) * 8)];
            }
            __builtin_amdgcn_s_setprio(1);
            #pragma unroll
            for (int mi = 0; mi < 4; ++mi)
                #pragma unroll
                for (int nj = 0; nj < 4; ++nj)
                    acc[mi][nj] = __builtin_amdgcn_mfma_f32_16x16x32_bf16(
                        af[mi], bfr[nj], acc[mi][nj], 0, 0, 0);
            __builtin_amdgcn_s_setprio(0);
        }

        __builtin_amdgcn_sched_barrier(0);
        __builtin_amdgcn_s_barrier();
        if (t + 2 < 16) STAGE(cur, (t + 2) * 64);
    }

    if (MODE == 0) {
        ushort* LB = (ushort*)As;                    // 32 KB bounce
        const int bB = brow >> 11, t0 = brow & (SEQ - 1);
        if (blockIdx.z == 2) {
            #pragma unroll
            for (int mi = 0; mi < 4; ++mi)
                #pragma unroll
                for (int nj = 0; nj < 4; ++nj) {
                    int tlb = 64 * wr + 16 * mi + 4 * g;
                    int hd = 16 * nj + l15;
                    int sI = (tlb >> 3) * 2 + wc;
                    uint2 pk;
                    pk.x = cvtpk_bf16(acc[mi][nj][0], acc[mi][nj][1]);
                    pk.y = cvtpk_bf16(acc[mi][nj][2], acc[mi][nj][3]);
                    *(uint2*)&LB[sI * 512 + hd * 8 + (tlb & 7)] = pk;
                }
            __syncthreads();
            #pragma unroll
            for (int j = 0; j < 8; ++j) {
                int4 v = *(const int4*)&LB[(j * 256 + tid) * 8];
                int sI = j * 4 + (tid >> 6);
                size_t base = (size_t)(bB * NH + 2 * blockIdx.y + (sI & 1)) * (SEQ * HD)
                            + (size_t)((t0 >> 3) + (sI >> 1)) * 512 + (tid & 63) * 8;
                *(int4*)&Dst[base] = v;
            }
        } else {
            const float osc = (blockIdx.z == 0) ? 0.125f * 1.44269504f : 1.0f;
            #pragma unroll
            for (int mi = 0; mi < 4; ++mi)
                #pragma unroll
                for (int nj = 0; nj < 4; ++nj)
                    #pragma unroll
                    for (int reg = 0; reg < 4; ++reg) {
                        int tl = 64 * wr + 16 * mi + 4 * g + reg;
                        int hd = 16 * nj + l15;
                        int sI = (tl >> 5) * 2 + wc;
                        LB[sI * 2048 + (hd >> 3) * 256 + (tl & 31) * 8 + (hd & 7)] =
                            f2bf(acc[mi][nj][reg] * osc);
                    }
            __syncthreads();
            #pragma unroll
            for (int j = 0; j < 8; ++j) {
                int4 v = *(const int4*)&LB[(j * 256 + tid) * 8];
                size_t base = (size_t)(bB * NH + 2 * blockIdx.y + (j & 1)) * (SEQ * HD)
                            + (size_t)((t0 >> 5) + (j >> 1)) * 2048 + tid * 8;
                *(int4*)&Dst[base] = v;
            }
        }
    } else {
        #pragma unroll
        for (int nj = 0; nj < 4; ++nj) {
            int col = bcol + 64 * wc + 16 * nj + l15;
            float bv = bias[col];
            #pragma unroll
            for (int mi = 0; mi < 4; ++mi)
                #pragma unroll
                for (int reg = 0; reg < 4; ++reg) {
                    int row = brow + 64 * wr + 16 * mi + 4 * g + reg;
                    Fout[(size_t)row * DIM + col] = acc[mi][nj][reg] + bv;
                }
        }
    }
}

// ---------------------------------------------------------------------------
// Flash attention v12 = v11 + VALU bloat removal:
//   (a) exp2f -> raw v_exp_f32 (OCML exp2 carries ~5 extra VALU ops/call;
//       32 calls/body). P only needs bf16 precision; denormal flush ok.
//   (b) pointer-carry addressing: 4 base pointers (K f0/f1, V lo/hi), all
//       16 body loads use 13-bit immediate offsets (<=3072B), pointers
//       advance +8192B once per body (8 VALU replaces ~64).
// Structure unchanged: grid 32x64 longest-first, 4-wave split-KV, QK-ahead
// pipeline, defer-max, cvt_pk+permlane P, LSE merge in LDS.
// ---------------------------------------------------------------------------
__global__ __launch_bounds__(256, 2)
void attn_mfma12(const ushort* __restrict__ q, const ushort* __restrict__ k,
                 const ushort* __restrict__ vt, ushort* __restrict__ ctx)
{
    __shared__ float Olds[4 * 2048];     // [w][d][q^(d&31)]  32 KB
    __shared__ float Mlds[4][32];
    __shared__ float Llds[4][32];

    const int tid = threadIdx.x;
    const int wq = tid >> 6, l = tid & 63;
    const int l31 = l & 31, h = l >> 5;
    const int bh = blockIdx.x;                // 0..31: XCD affinity = bh%8
    const int qt = 63 - (int)blockIdx.y;      // longest-first
    const int qlo = qt * 32;
    const int nt  = (qt >> 1) + 1;
    const int cnt = (nt + 3) >> 2;
    const int kt0 = wq * cnt;
    const int kt1 = min(nt, kt0 + cnt);

    const ushort* Qg = q  + (size_t)bh * SEQ * HD;
    const ushort* Kg = k  + (size_t)bh * SEQ * HD;
    const ushort* Vg = vt + (size_t)bh * SEQ * HD;

    bf16x8 qf[4];
    #pragma unroll
    for (int s = 0; s < 4; ++s)
        qf[s] = *(const bf16x8*)&Qg[(((size_t)qt * 8 + 2 * s + h) * 32 + l31) * 8];

    f32x16 o[2] = {};
    float m = -3.0e38f, lsum = 0.f;

    if (kt0 < kt1) {
        bf16x8 kfA[8], kfB[8];
        f32x16 stA[2], stB[2];

        // prologue: K(kt0) -> kfA; QK(kt0) -> stA; K(kt0+1) -> kfB
        #pragma unroll
        for (int s = 0; s < 4; ++s)
            #pragma unroll
            for (int f = 0; f < 2; ++f)
                kfA[2 * s + f] = *(const bf16x8*)
                    &Kg[(((size_t)(2 * kt0 + f) * 8 + 2 * s + h) * 32 + l31) * 8];
        stA[0] = (f32x16){}; stA[1] = (f32x16){};
        #pragma unroll
        for (int s = 0; s < 4; ++s)
            #pragma unroll
            for (int f = 0; f < 2; ++f)
                stA[f] = __builtin_amdgcn_mfma_f32_32x32x16_bf16(
                    kfA[2 * s + f], qf[s], stA[f], 0, 0, 0);
        if (kt0 + 1 < kt1) {
            #pragma unroll
            for (int s = 0; s < 4; ++s)
                #pragma unroll
                for (int f = 0; f < 2; ++f)
                    kfB[2 * s + f] = *(const bf16x8*)
                        &Kg[(((size_t)(2 * kt0 + 2 + f) * 8 + 2 * s + h) * 32 + l31) * 8];
        }

        // pointer-carry bases: K at tile kt0+2 (f0/f1), V at tile kt0 (lo/hi)
        const ushort* kpa = Kg + (((size_t)(16 * (kt0 + 2)) + h) * 32 + l31) * 8;
        const ushort* kpb = kpa + 2048;
        const ushort* vpa = Vg + (((size_t)(8 * kt0) + h) * 64 + l31) * 8;
        const ushort* vpb = vpa + 2048;

        auto body = [&](f32x16 (&stC)[2], f32x16 (&stN)[2],
                        bf16x8 (&kcN)[8], bf16x8 (&kcL)[8], int kt) {
            const int kvb = 64 * kt;

            // V loads for current tile (imm-offset from vpa/vpb)
            bf16x8 vf[8];
            #pragma unroll
            for (int s4 = 0; s4 < 4; ++s4)
                #pragma unroll
                for (int dt = 0; dt < 2; ++dt)
                    vf[2 * s4 + dt] = *(const bf16x8*)
                        ((s4 < 2 ? vpa : vpb) + (s4 & 1) * 1024 + dt * 256);

            // QK^T for NEXT tile (MFMA drains under this body's softmax)
            if (kt + 1 < kt1) {
                stN[0] = (f32x16){}; stN[1] = (f32x16){};
                __builtin_amdgcn_s_setprio(1);
                #pragma unroll
                for (int s = 0; s < 4; ++s)
                    #pragma unroll
                    for (int f = 0; f < 2; ++f)
                        stN[f] = __builtin_amdgcn_mfma_f32_32x32x16_bf16(
                            kcN[2 * s + f], qf[s], stN[f], 0, 0, 0);
                __builtin_amdgcn_s_setprio(0);
            }

            // K loads for kt+2 (imm-offset from kpa/kpb)
            if (kt + 2 < kt1) {
                #pragma unroll
                for (int s = 0; s < 4; ++s)
                    #pragma unroll
                    for (int f = 0; f < 2; ++f)
                        kcL[2 * s + f] = *(const bf16x8*)
                            ((f ? kpb : kpa) + s * 512);
            }

            // causal mask (only straddling tile)
            const int qg = qlo + l31;
            if (kvb + 63 > qlo) {
                #pragma unroll
                for (int f = 0; f < 2; ++f)
                    #pragma unroll
                    for (int r = 0; r < 16; ++r) {
                        int kvg = kvb + 32 * f + (r & 3) + 8 * (r >> 2) + 4 * h;
                        if (kvg > qg) stC[f][r] = -INFINITY;
                    }
            }

            // row max via max3 chains
            float ca, cb;
            ca = fmax3(stC[0][0], stC[0][1], stC[0][2]);
            cb = fmax3(stC[0][3], stC[0][4], stC[0][5]);
            ca = fmax3(ca, stC[0][6], stC[0][7]);
            cb = fmax3(cb, stC[0][8], stC[0][9]);
            ca = fmax3(ca, stC[0][10], stC[0][11]);
            cb = fmax3(cb, stC[0][12], stC[0][13]);
            ca = fmax3(ca, stC[0][14], stC[0][15]);
            float t0 = fmaxf(ca, cb);
            ca = fmax3(stC[1][0], stC[1][1], stC[1][2]);
            cb = fmax3(stC[1][3], stC[1][4], stC[1][5]);
            ca = fmax3(ca, stC[1][6], stC[1][7]);
            cb = fmax3(cb, stC[1][8], stC[1][9]);
            ca = fmax3(ca, stC[1][10], stC[1][11]);
            cb = fmax3(cb, stC[1][12], stC[1][13]);
            ca = fmax3(ca, stC[1][14], stC[1][15]);
            float tmax = fmax3(t0, ca, cb);
            {
                union { float f; unsigned u; } tm; tm.f = tmax;
                u32x2 ts = __builtin_amdgcn_permlane32_swap(tm.u, tm.u, false, false);
                union { unsigned u; float f; } to; to.u = h ? ts.x : ts.y;
                tmax = fmaxf(tmax, to.f);
            }

            if (!__all(tmax - m <= 8.0f)) {          // T13 defer-max
                float mn = fmaxf(m, tmax);
                float sc = exp2_asm(m - mn);
                lsum *= sc;
                f32x2 sc2 = {sc, sc};
                #pragma unroll
                for (int dt = 0; dt < 2; ++dt) {
                    f32x2* po = (f32x2*)&o[dt];
                    #pragma unroll
                    for (int i = 0; i < 8; ++i) po[i] = pk_mul(po[i], sc2);
                }
                m = mn;
            }

            // exp + packed sums (raw v_exp_f32)
            f32x2 mneg = {-m, -m};
            f32x2 a0 = {0.f, 0.f}, a1 = {0.f, 0.f}, a2 = {0.f, 0.f}, a3 = {0.f, 0.f};
            #pragma unroll
            for (int f = 0; f < 2; ++f) {
                f32x2* pp = (f32x2*)&stC[f];
                #pragma unroll
                for (int i = 0; i < 8; ++i) {
                    f32x2 t = pk_add(pp[i], mneg);
                    t.x = exp2_asm(t.x); t.y = exp2_asm(t.y);
                    pp[i] = t;
                    if ((i & 3) == 0)      a0 = pk_add(a0, t);
                    else if ((i & 3) == 1) a1 = pk_add(a1, t);
                    else if ((i & 3) == 2) a2 = pk_add(a2, t);
                    else                   a3 = pk_add(a3, t);
                }
            }
            a0 = pk_add(a0, a1);
            a2 = pk_add(a2, a3);
            a0 = pk_add(a0, a2);
            lsum += a0.x + a0.y;

            // P -> PA frags: cvt_pk + permlane32_swap (T12), PV MFMAs
            #pragma unroll
            for (int s4 = 0; s4 < 4; ++s4) {
                const int f = s4 >> 1, rb2 = 8 * (s4 & 1);
                unsigned Aa = cvtpk_bf16(stC[f][rb2 + 0], stC[f][rb2 + 1]);
                unsigned Bb = cvtpk_bf16(stC[f][rb2 + 2], stC[f][rb2 + 3]);
                unsigned Cc = cvtpk_bf16(stC[f][rb2 + 4], stC[f][rb2 + 5]);
                unsigned Dd = cvtpk_bf16(stC[f][rb2 + 6], stC[f][rb2 + 7]);
                u32x2 r02 = __builtin_amdgcn_permlane32_swap(Aa, Cc, false, false);
                u32x2 r13 = __builtin_amdgcn_permlane32_swap(Bb, Dd, false, false);
                union { unsigned wv[4]; bf16x8 v; } pu;
                pu.wv[0] = r02.x;
                pu.wv[1] = r13.x;
                pu.wv[2] = r02.y;
                pu.wv[3] = r13.y;
                __builtin_amdgcn_s_setprio(1);
                #pragma unroll
                for (int dt = 0; dt < 2; ++dt)
                    o[dt] = __builtin_amdgcn_mfma_f32_32x32x16_bf16(
                        vf[2 * s4 + dt], pu.v, o[dt], 0, 0, 0);
                __builtin_amdgcn_s_setprio(0);
            }

            // advance carried pointers (one K tile / one V tile)
            kpa += 4096; kpb += 4096;
            vpa += 4096; vpb += 4096;
        };

        int kt = kt0;
        while (true) {
            body(stA, stB, kfB, kfA, kt);
            if (++kt >= kt1) break;
            body(stB, stA, kfA, kfB, kt);
            if (++kt >= kt1) break;
        }
    }

    // ---- LSE merge across the block's 4 waves ----
    float lt = lsum + __shfl_xor(lsum, 32);
    if (h == 0) Mlds[wq][l31] = m;
    __syncthreads();
    float ms = fmaxf(fmaxf(Mlds[0][l31], Mlds[1][l31]),
                     fmaxf(Mlds[2][l31], Mlds[3][l31]));
    float fw = exp2_asm(m - ms);
    if (h == 0) Llds[wq][l31] = lt * fw;
    #pragma unroll
    for (int dt = 0; dt < 2; ++dt)
        #pragma unroll
        for (int r = 0; r < 16; ++r) {
            int d = 32 * dt + (r & 3) + 8 * (r >> 2) + 4 * h;
            Olds[wq * 2048 + d * 32 + (l31 ^ (d & 31))] = o[dt][r] * fw;
        }
    __syncthreads();

    // combine + coalesced write: thread -> (q = tid>>3, d-chunk = tid&7)
    const int tq = tid >> 3, tc = tid & 7;
    float inv = 1.0f / (Llds[0][tq] + Llds[1][tq] + Llds[2][tq] + Llds[3][tq]);
    union { ushort u[8]; int4 v4; } ov;
    #pragma unroll
    for (int i = 0; i < 8; i += 2) {
        int d0 = 8 * tc + i, d1 = d0 + 1;
        float s0 = 0.f, s1 = 0.f;
        #pragma unroll
        for (int ww = 0; ww < 4; ++ww) {
            s0 += Olds[ww * 2048 + d0 * 32 + (tq ^ (d0 & 31))];
            s1 += Olds[ww * 2048 + d1 * 32 + (tq ^ (d1 & 31))];
        }
        *(unsigned*)&ov.u[i] = cvtpk_bf16(s0 * inv, s1 * inv);
    }
    ushort* Cg = ctx + (size_t)bh * SEQ * HD + (size_t)qlo * HD;
    *(int4*)&Cg[tq * 64 + 8 * tc] = ov.v4;
}

// ---------------------------------------------------------------------------
extern "C" void kernel_launch(void* const* d_in, const int* in_sizes, int n_in,
                              void* d_out, int out_size, void* d_ws, size_t ws_size,
                              hipStream_t stream)
{
    (void)in_sizes; (void)n_in; (void)out_size; (void)ws_size;
    const float* x  = (const float*)d_in[0];
    const float* Wq = (const float*)d_in[1];
    const float* Wk = (const float*)d_in[2];
    const float* Wv = (const float*)d_in[3];
    const float* Wo = (const float*)d_in[4];
    const float* bo = (const float*)d_in[5];
    float* out = (float*)d_out;

    ushort* wsu  = (ushort*)d_ws;
    ushort* xb   = wsu;                      // 4M
    ushort* wqb  = wsu + 4194304;            // 1M each
    ushort* wkb  = wsu + 5242880;
    ushort* wvb  = wsu + 6291456;
    ushort* wob  = wsu + 7340032;
    ushort* qbuf = wsu + 8388608;            // 4M, Q fragment-major, *0.125*log2e
    ushort* kbuf = wsu + 12582912;           // 4M, K fragment-major
    ushort* vtb  = wsu + 16777216;           // 4M, V^T fragment-major
    ushort* ctxb = wsu + 20971520;           // 4M, flat == [B*T, D]

    cast_all<<<dim3(512, 5), 256, 0, stream>>>(x, Wq, Wk, Wv, Wo,
                                               xb, wqb, wkb, wvb, wob);

    dim3 gqkv(MTOT / 128, DIM / 128, 3);
    gemm_bf16<0><<<gqkv, 256, 0, stream>>>(xb, wqb, wkb, wvb,
                                           qbuf, kbuf, vtb, nullptr, nullptr);

    dim3 ga(BATCH * NH, SEQ / 32);
    attn_mfma12<<<ga, 256, 0, stream>>>(qbuf, kbuf, vtb, ctxb);

    dim3 go(MTOT / 128, DIM / 128, 1);
    gemm_bf16<1><<<go, 256, 0, stream>>>(ctxb, wob, nullptr, nullptr,
                                         nullptr, nullptr, nullptr, bo, out);
}